// Round 12
// baseline (276.478 us; speedup 1.0000x reference)
//
#include <hip/hip_runtime.h>
#include <cstdint>
#include <cstddef>

// C[4096,4096] = sum_r input[r] @ weight[r]^T  == GEMM M=N=4096, K=8192, fp32 out.
// Phase 1: fp32 -> bf16 linear cast (unchanged — at BW roofline).
// Phase 2 (R12): 256x256-tile bf16 MFMA GEMM, one barrier per K-tile.
//   R10 (203.8us, 63.1%): interval opened with 96-read flood covered only by
//   Q4 -> ~530 cyc MFMA idle. R11 (230us, 52.9%): moved Q3 after the barrier
//   BUT also moved staging to mid-interval -> vmcnt slack 2700->1250 cyc ->
//   regression. R12 = R11's quad order + R10's early staging (single change
//   vs R11: stages at interval TOP).
//   Interval I(t) (buf[(t+1)&1] holds tile t+1, stage target = buf[t&1]):
//     stage tile(t+2) -> buf[t&1]    [8 gll16, issued first => ~full-interval
//                                     slack before the end-of-interval drain]
//     Q3(t): aLo,bHi                 [covers nothing yet - regs only]
//     read aLo,bLo(t+1)              [12/wave; flood covered by Q3]
//     Q4(t): aHi,bHi
//     read aHi,bHi(t+1)              [12/wave; covered by Q4]
//     Q1(t+1); Q2(t+1)               [consume fresh lo frags]
//     vmcnt(0) ; BAR ; sched_barrier(0)
//   Hazards: stage->buf[t&1] at I(t) top: tile-t frags in that buffer were
//   lgkm-consumed by Q1(t)/Q2(t) BEFORE I(t-1)'s barrier ✓. Reads of
//   buf[(t+1)&1]: staged in I(t-1), drained by its vmcnt(0)+BAR ✓. Register
//   WARs by program order (aLo/bLo re-read after Q3; aHi/bHi after Q4).
//   vmcnt(0) at I(t) end drains exactly t+2's 8 loads.

#define M_DIM 4096
#define N_DIM 4096
#define K_DIM 8192
#define K_LOCAL 1024
#define RANKS 8

typedef __bf16 bf16x8 __attribute__((ext_vector_type(8)));
typedef float f32x4 __attribute__((ext_vector_type(4)));

__device__ __forceinline__ unsigned short f2bf(float f) {
    unsigned int u = __float_as_uint(f);
    unsigned int r = (u + 0x7fffu + ((u >> 16) & 1u)) >> 16;
    return (unsigned short)r;
}

// ---------- Phase 1: linear fp32 -> bf16 cast ----------
__global__ __launch_bounds__(256) void convert_cast(
    const float* __restrict__ srcA, unsigned short* __restrict__ dstA,
    const float* __restrict__ srcB, unsigned short* __restrict__ dstB,
    int blocks_per_tensor) {
    const float* src = srcA;
    unsigned short* dst = dstA;
    int b = blockIdx.x;
    if (b >= blocks_per_tensor) { b -= blocks_per_tensor; src = srcB; dst = dstB; }
    size_t base = (size_t)b * 4096 + threadIdx.x * 4;
#pragma unroll
    for (int i = 0; i < 4; ++i) {
        size_t e = base + i * 1024;
        f32x4 v = __builtin_nontemporal_load((const f32x4*)(src + e));
        ushort4 o;
        o.x = f2bf(v.x); o.y = f2bf(v.y); o.z = f2bf(v.z); o.w = f2bf(v.w);
        *(ushort4*)(dst + e) = o;
    }
}

// ---------- shared helpers ----------
__device__ __forceinline__ void gll16(const unsigned short* g, unsigned short* l) {
    __builtin_amdgcn_global_load_lds(
        (const __attribute__((address_space(1))) void*)g,
        (__attribute__((address_space(3))) void*)l,
        16, 0, 0);
}

__device__ __forceinline__ int k_off(int t) {
    // element offset of K-tile t in [R][4096][K_LOCAL]: r = t>>4, kl = (t&15)*64
    return ((t >> 4) << 22) | ((t & 15) << 6);
}

// ---------- Phase 2 macros ----------
// LDS (ushorts): A[buf][half] at (buf*2+half)*8192, B at 32768 + same. 128 KiB.
#define VM0 asm volatile("s_waitcnt vmcnt(0)" ::: "memory")
#define VMNONE ((void)0)
#define BAR __builtin_amdgcn_s_barrier();

#define STAGE_A(TOFF, HALF, PBUF) { \
    _Pragma("unroll") for (int j_ = 0; j_ < 2; ++j_) \
        gll16(A + (size_t)((TOFF) + (HALF) * 131072 + thrA[j_]), \
              smem + (PBUF) * 16384 + (HALF) * 8192 + ldsOff[j_]); }

#define STAGE_B(TOFF, HALF, PBUF) { \
    _Pragma("unroll") for (int j_ = 0; j_ < 2; ++j_) \
        gll16(B + (size_t)((TOFF) + (HALF) * 131072 + thrB[j_]), \
              smem + 32768 + (PBUF) * 16384 + (HALF) * 8192 + ldsOff[j_]); }

#define READ_A(DST, BASE, MOFF) { \
    _Pragma("unroll") for (int ks_ = 0; ks_ < 2; ++ks_) \
        _Pragma("unroll") for (int mm_ = 0; mm_ < 4; ++mm_) \
            DST[ks_][mm_] = *(const bf16x8*)&(BASE)[(((MOFF) + mm_) * 16 + l15) * 64 + (ks_ ? swz1 : swz0)]; }

#define READ_B(DST, BASE, NJ0) { \
    _Pragma("unroll") for (int ks_ = 0; ks_ < 2; ++ks_) \
        _Pragma("unroll") for (int nn_ = 0; nn_ < 2; ++nn_) \
            DST[ks_][nn_] = *(const bf16x8*)&(BASE)[(bRowBase + ((NJ0) + nn_) * 16 + l15) * 64 + (ks_ ? swz1 : swz0)]; }

#define QUAD(AF, BF, MI0, NJ0) { \
    __builtin_amdgcn_s_setprio(1); \
    _Pragma("unroll") for (int ks_ = 0; ks_ < 2; ++ks_) \
        _Pragma("unroll") for (int mm_ = 0; mm_ < 4; ++mm_) \
            _Pragma("unroll") for (int nn_ = 0; nn_ < 2; ++nn_) \
                acc[(MI0) + mm_][(NJ0) + nn_] = __builtin_amdgcn_mfma_f32_16x16x32_bf16( \
                    AF[ks_][mm_], BF[ks_][nn_], acc[(MI0) + mm_][(NJ0) + nn_], 0, 0, 0); \
    __builtin_amdgcn_s_setprio(0); }

// Interval I(t): stages first (max vmcnt slack), Q3/Q4 of t cover the read
// flood of t+1, Q1/Q2 of t+1 close the interval.
// PN = (t+1)&1 (buffer holding tile t+1); stage target = PN^1 = t&1.
#define KINT(PN, KT, S, SR, VMOP) { \
    unsigned short* aN_ = smem + (PN) * 16384 + wmIdx * 8192; \
    unsigned short* bN_ = smem + 32768 + (PN) * 16384 + bHalfSel * 8192; \
    const int t2off_ = k_off((KT) + 2); \
    if (S) { STAGE_A(t2off_, 0, (PN) ^ 1) STAGE_A(t2off_, 1, (PN) ^ 1) \
             STAGE_B(t2off_, 0, (PN) ^ 1) STAGE_B(t2off_, 1, (PN) ^ 1) } \
    QUAD(aLo, bHi, 0, 2)                              /* Q3(t) */ \
    if (SR) { READ_A(aLo, aN_, 0) READ_B(bLo, bN_, 0) } \
    QUAD(aHi, bHi, 4, 2)                              /* Q4(t) */ \
    if (SR) { READ_A(aHi, aN_, 4) READ_B(bHi, bN_, 2) } \
    if (SR) { QUAD(aLo, bLo, 0, 0) QUAD(aHi, bLo, 4, 0) }  /* Q1,Q2(t+1) */ \
    VMOP; \
    BAR \
    __builtin_amdgcn_sched_barrier(0); \
}

__global__ __launch_bounds__(512, 2) void gemm_bf16_8ph(
    const unsigned short* __restrict__ A,  // [R, M, K_LOCAL] bf16
    const unsigned short* __restrict__ B,  // [R, N, K_LOCAL] bf16
    float* __restrict__ C) {               // [M, N] fp32
    extern __shared__ unsigned short smem[];  // 131072 B

    const int tid = threadIdx.x;
    const int lane = tid & 63;
    const int wave = tid >> 6;        // 0..7
    const int wmIdx = wave >> 2;      // 0..1  (128-row M half)
    const int wn = wave & 3;          // 0..3  (64-col N slice)
    const int l15 = lane & 15;
    const int l4 = lane >> 4;
    const int bHalfSel = wn >> 1;
    const int bRowBase = (wn & 1) * 64;

    // XCD-aware mapping: 16x16 tile grid; XCD x owns an 8x4 region.
    const int bid = blockIdx.x;       // 0..255
    const int xcd = bid & 7;
    const int idx = bid >> 3;         // 0..31
    const int tm = (xcd >> 2) * 8 + (idx >> 2);
    const int tn = (xcd & 3) * 4 + (idx & 3);
    const int bm0 = tm * 256;
    const int bn0 = tn * 256;

    // Staging offsets: half-tile = 128 rows x 64 cols; chunk cc = j*512 + tid
    // -> (row = cc>>3, pos = cc&7), XOR swizzle applied on the global source.
    int thrA[2], thrB[2], ldsOff[2];
#pragma unroll
    for (int j = 0; j < 2; ++j) {
        int cc = j * 512 + tid;
        int row = cc >> 3;
        int col = ((cc & 7) ^ (row & 7)) * 8;
        thrA[j] = (bm0 + row) * K_LOCAL + col;
        thrB[j] = (bn0 + row) * K_LOCAL + col;
        ldsOff[j] = cc * 8;
    }

    const int swz0 = ((0 + l4) ^ (l15 & 7)) * 8;  // ks = 0
    const int swz1 = ((4 + l4) ^ (l15 & 7)) * 8;  // ks = 1

    bf16x8 aLo[2][4], aHi[2][4], bLo[2][2], bHi[2][2];
    f32x4 acc[8][4] = {};

    // Prologue: stage tile0 -> buf0; drain; read ALL tile-0 frags; stage
    // tile1 -> buf1; Q1(0), Q2(0); drain tile1; barrier -> enter I(0).
    STAGE_A(0, 0, 0)
    STAGE_A(0, 1, 0)
    STAGE_B(0, 0, 0)
    STAGE_B(0, 1, 0)
    VM0;
    BAR
    {
        unsigned short* a0_ = smem + wmIdx * 8192;
        unsigned short* b0_ = smem + 32768 + bHalfSel * 8192;
        READ_A(aLo, a0_, 0)
        READ_B(bLo, b0_, 0)
        READ_A(aHi, a0_, 4)
        READ_B(bHi, b0_, 2)
    }
    {
        const int t1off = k_off(1);
        STAGE_A(t1off, 0, 1)
        STAGE_A(t1off, 1, 1)
        STAGE_B(t1off, 0, 1)
        STAGE_B(t1off, 1, 1)
    }
    QUAD(aLo, bLo, 0, 0)
    QUAD(aHi, bLo, 4, 0)
    VM0;
    BAR
    __builtin_amdgcn_sched_barrier(0);

#pragma unroll 1
    for (int kt = 0; kt < 126; kt += 2) {
        KINT(1, kt, 1, 1, VM0)       // I(t even): reads buf1, stages buf0
        KINT(0, kt + 1, 1, 1, VM0)   // I(t odd):  reads buf0, stages buf1
    }
    KINT(1, 126, 0, 1, VMNONE)       // reads tile 127 (staged I(125)); no stage
    KINT(0, 127, 0, 0, VMNONE)       // Q3(127), Q4(127) only

    // epilogue: C/D layout col = lane&15, row = (lane>>4)*4 + reg
#pragma unroll
    for (int mi = 0; mi < 8; ++mi) {
        int row0 = bm0 + wmIdx * 128 + mi * 16 + l4 * 4;
#pragma unroll
        for (int nj = 0; nj < 4; ++nj) {
            int col = bn0 + wn * 64 + nj * 16 + l15;
#pragma unroll
            for (int r = 0; r < 4; ++r)
                C[(size_t)(row0 + r) * N_DIM + col] = acc[mi][nj][r];
        }
    }
}

// ---------- Fallback A: 128x128 m97-structure kernel ----------
__global__ __launch_bounds__(256) void gemm_bf16_128(
    const unsigned short* __restrict__ A,
    const unsigned short* __restrict__ B,
    float* __restrict__ C) {
    __shared__ __align__(16) unsigned short As[128 * 64];
    __shared__ __align__(16) unsigned short Bs[128 * 64];

    const int tid = threadIdx.x;
    const int lane = tid & 63;
    const int wave = tid >> 6;
    const int wm = (wave >> 1) * 64;
    const int wnn = (wave & 1) * 64;
    const int l15 = lane & 15;
    const int l4 = lane >> 4;

    const int bid = blockIdx.x;
    const int xcd = bid & 7;
    const int q = bid >> 3;
    const int st = (q >> 2) * 8 + xcd;
    const int pos = q & 3;
    const int bm0 = ((st >> 4) * 2 + (pos >> 1)) * 128;
    const int bn0 = ((st & 15) * 2 + (pos & 1)) * 128;

    const unsigned short* ga[4];
    const unsigned short* gb[4];
    int lo[4];
#pragma unroll
    for (int p = 0; p < 4; ++p) {
        int cc = p * 256 + tid;
        int row = cc >> 3;
        int cpos = cc & 7;
        int col = (cpos ^ (row & 7)) * 8;
        ga[p] = A + (size_t)(bm0 + row) * K_LOCAL + col;
        gb[p] = B + (size_t)(bn0 + row) * K_LOCAL + col;
        lo[p] = cc * 8;
    }

    const int swz0 = ((l4 + 0) ^ (l15 & 7)) * 8;
    const int swz1 = ((l4 + 4) ^ (l15 & 7)) * 8;
    const int a_row = (wm + l15) * 64;
    const int b_row = (wnn + l15) * 64;

    f32x4 acc[4][4] = {};

    for (int r = 0; r < RANKS; ++r) {
        const size_t roff = (size_t)r * (M_DIM * (size_t)K_LOCAL);
        for (int kl = 0; kl < K_LOCAL; kl += 64) {
#pragma unroll
            for (int p = 0; p < 4; ++p) {
                gll16(ga[p] + roff + kl, &As[lo[p]]);
                gll16(gb[p] + roff + kl, &Bs[lo[p]]);
            }
            __syncthreads();
#pragma unroll
            for (int ks = 0; ks < 2; ++ks) {
                const int swz = ks ? swz1 : swz0;
                bf16x8 af[4], bfr[4];
#pragma unroll
                for (int i = 0; i < 4; ++i)
                    af[i] = *(const bf16x8*)&As[a_row + i * 16 * 64 + swz];
#pragma unroll
                for (int j = 0; j < 4; ++j)
                    bfr[j] = *(const bf16x8*)&Bs[b_row + j * 16 * 64 + swz];
#pragma unroll
                for (int i = 0; i < 4; ++i)
#pragma unroll
                    for (int j = 0; j < 4; ++j)
                        acc[i][j] = __builtin_amdgcn_mfma_f32_16x16x32_bf16(
                            af[i], bfr[j], acc[i][j], 0, 0, 0);
            }
            __syncthreads();
        }
    }

#pragma unroll
    for (int i = 0; i < 4; ++i) {
        int row0 = bm0 + wm + i * 16 + l4 * 4;
#pragma unroll
        for (int j = 0; j < 4; ++j) {
            int col = bn0 + wnn + j * 16 + l15;
#pragma unroll
            for (int r = 0; r < 4; ++r)
                C[(size_t)(row0 + r) * N_DIM + col] = acc[i][j][r];
        }
    }
}

// ---------- Fallback B (ws too small): naive fp32 tiled GEMM ----------
__global__ void gemm_naive(const float* __restrict__ A, const float* __restrict__ B,
                           float* __restrict__ C) {
    __shared__ float As[16][17];
    __shared__ float Bs[16][17];
    int tx = threadIdx.x, ty = threadIdx.y;
    int m = blockIdx.y * 16 + ty;
    int n0 = blockIdx.x * 16;
    float accv = 0.f;
    for (int kt = 0; kt < K_DIM; kt += 16) {
        int r = kt >> 10;
        int k = (kt & 1023) + tx;
        As[ty][tx] = A[((size_t)r * M_DIM + m) * K_LOCAL + k];
        Bs[ty][tx] = B[((size_t)r * N_DIM + (n0 + ty)) * K_LOCAL + k];
        __syncthreads();
#pragma unroll
        for (int kk = 0; kk < 16; ++kk) accv += As[ty][kk] * Bs[tx][kk];
        __syncthreads();
    }
    C[(size_t)m * N_DIM + n0 + tx] = accv;
}

extern "C" void kernel_launch(void* const* d_in, const int* in_sizes, int n_in,
                              void* d_out, int out_size, void* d_ws, size_t ws_size,
                              hipStream_t stream) {
    const float* inp = (const float*)d_in[0];
    const float* wgt = (const float*)d_in[1];
    float* out = (float*)d_out;

    const size_t elems = (size_t)M_DIM * K_DIM;              // 33,554,432 per tensor
    const size_t need = 2 * elems * sizeof(unsigned short);  // 128 MiB

    if (ws_size >= need) {
        unsigned short* Abf = (unsigned short*)d_ws;
        unsigned short* Bbf = Abf + elems;
        const int bpt = (int)(elems / 4096);  // 8192 blocks per tensor
        convert_cast<<<bpt * 2, 256, 0, stream>>>(inp, Abf, wgt, Bbf, bpt);

        static int dynOK = -1;
        if (dynOK < 0) {
            dynOK = (hipFuncSetAttribute((const void*)gemm_bf16_8ph,
                                         hipFuncAttributeMaxDynamicSharedMemorySize,
                                         131072) == hipSuccess)
                        ? 1
                        : 0;
        }
        if (dynOK) {
            gemm_bf16_8ph<<<256, 512, 131072, stream>>>(Abf, Bbf, out);
        } else {
            gemm_bf16_128<<<1024, 256, 0, stream>>>(Abf, Bbf, out);
        }
    } else {
        dim3 grid(N_DIM / 16, M_DIM / 16);
        dim3 block(16, 16);
        gemm_naive<<<grid, block, 0, stream>>>(inp, wgt, out);
    }
}

// Round 13
// 259.266 us; speedup vs baseline: 1.0664x; 1.0664x over previous
//
#include <hip/hip_runtime.h>
#include <cstdint>
#include <cstddef>

// C[4096,4096] = sum_r input[r] @ weight[r]^T  == GEMM M=N=4096, K=8192, fp32 out.
// Phase 1: fp32 -> bf16 linear cast (at BW roofline).
// Phase 2 (R13 = R10 verbatim): 256x256-tile bf16 MFMA GEMM, ONE barrier/K-tile.
//   Session ledger: depth (R3 null), DS balance (R6 null), 2 blk/CU (R9 -1%),
//   read-ahead (R4 +7%), single-barrier lag-1 dbuf (R10 +8%), quad
//   fragmentation (R11/R12 -12% BOTH placements -> falsified). R10's monolithic
//   Q1+Q2+Q3 MFMA run (~1863 cyc/CU) is load-bearing: it lets the two
//   barrier-synced waves/SIMD slip phase so one wave's MFMA covers the other's
//   read+stage; fragmenting quads exposes lgkm waits at identical points in
//   both waves. Keep the long run.
//   Per K-tile t (buf p = t&1):
//     R1: read aHi(t)@p | stage ALL of t+1 -> p^1 (8 gll16, early => ~2700cyc
//         vmcnt slack) | Q1(aLo,bLo) | read bHi(t)@p | Q2(aHi,bLo) | Q3(aLo,bHi)
//     vmcnt(0) ; BAR ; sched_barrier(0)
//     R2: read aLo,bLo(t+1)@p^1 | Q4(aHi,bHi)
//   Hazards: stage(t+1->p^1)@R1(t): p^1's last reads (aHi/bHi of t-1) were
//   lgkm-consumed before Q3(t-1) < tile-(t-1) barrier < stage ✓. R2 reads of
//   p^1 follow vmcnt(0)+BAR ✓. Register WARs by program order. vmcnt(0) at
//   tile t drains exactly t+1's 8 loads.

#define M_DIM 4096
#define N_DIM 4096
#define K_DIM 8192
#define K_LOCAL 1024
#define RANKS 8

typedef __bf16 bf16x8 __attribute__((ext_vector_type(8)));
typedef float f32x4 __attribute__((ext_vector_type(4)));

__device__ __forceinline__ unsigned short f2bf(float f) {
    unsigned int u = __float_as_uint(f);
    unsigned int r = (u + 0x7fffu + ((u >> 16) & 1u)) >> 16;
    return (unsigned short)r;
}

// ---------- Phase 1: linear fp32 -> bf16 cast ----------
__global__ __launch_bounds__(256) void convert_cast(
    const float* __restrict__ srcA, unsigned short* __restrict__ dstA,
    const float* __restrict__ srcB, unsigned short* __restrict__ dstB,
    int blocks_per_tensor) {
    const float* src = srcA;
    unsigned short* dst = dstA;
    int b = blockIdx.x;
    if (b >= blocks_per_tensor) { b -= blocks_per_tensor; src = srcB; dst = dstB; }
    size_t base = (size_t)b * 4096 + threadIdx.x * 4;
#pragma unroll
    for (int i = 0; i < 4; ++i) {
        size_t e = base + i * 1024;
        f32x4 v = __builtin_nontemporal_load((const f32x4*)(src + e));
        ushort4 o;
        o.x = f2bf(v.x); o.y = f2bf(v.y); o.z = f2bf(v.z); o.w = f2bf(v.w);
        *(ushort4*)(dst + e) = o;
    }
}

// ---------- shared helpers ----------
__device__ __forceinline__ void gll16(const unsigned short* g, unsigned short* l) {
    __builtin_amdgcn_global_load_lds(
        (const __attribute__((address_space(1))) void*)g,
        (__attribute__((address_space(3))) void*)l,
        16, 0, 0);
}

__device__ __forceinline__ int k_off(int t) {
    // element offset of K-tile t in [R][4096][K_LOCAL]: r = t>>4, kl = (t&15)*64
    return ((t >> 4) << 22) | ((t & 15) << 6);
}

// ---------- Phase 2 macros ----------
// LDS (ushorts): A[buf][half] at (buf*2+half)*8192, B at 32768 + same. 128 KiB.
#define VM0 asm volatile("s_waitcnt vmcnt(0)" ::: "memory")
#define VMNONE ((void)0)
#define BAR __builtin_amdgcn_s_barrier();

#define STAGE_A(TOFF, HALF, PBUF) { \
    _Pragma("unroll") for (int j_ = 0; j_ < 2; ++j_) \
        gll16(A + (size_t)((TOFF) + (HALF) * 131072 + thrA[j_]), \
              smem + (PBUF) * 16384 + (HALF) * 8192 + ldsOff[j_]); }

#define STAGE_B(TOFF, HALF, PBUF) { \
    _Pragma("unroll") for (int j_ = 0; j_ < 2; ++j_) \
        gll16(B + (size_t)((TOFF) + (HALF) * 131072 + thrB[j_]), \
              smem + 32768 + (PBUF) * 16384 + (HALF) * 8192 + ldsOff[j_]); }

#define READ_A(DST, BASE, MOFF) { \
    _Pragma("unroll") for (int ks_ = 0; ks_ < 2; ++ks_) \
        _Pragma("unroll") for (int mm_ = 0; mm_ < 4; ++mm_) \
            DST[ks_][mm_] = *(const bf16x8*)&(BASE)[(((MOFF) + mm_) * 16 + l15) * 64 + (ks_ ? swz1 : swz0)]; }

#define READ_B(DST, BASE, NJ0) { \
    _Pragma("unroll") for (int ks_ = 0; ks_ < 2; ++ks_) \
        _Pragma("unroll") for (int nn_ = 0; nn_ < 2; ++nn_) \
            DST[ks_][nn_] = *(const bf16x8*)&(BASE)[(bRowBase + ((NJ0) + nn_) * 16 + l15) * 64 + (ks_ ? swz1 : swz0)]; }

#define QUAD(AF, BF, MI0, NJ0) { \
    __builtin_amdgcn_s_setprio(1); \
    _Pragma("unroll") for (int ks_ = 0; ks_ < 2; ++ks_) \
        _Pragma("unroll") for (int mm_ = 0; mm_ < 4; ++mm_) \
            _Pragma("unroll") for (int nn_ = 0; nn_ < 2; ++nn_) \
                acc[(MI0) + mm_][(NJ0) + nn_] = __builtin_amdgcn_mfma_f32_16x16x32_bf16( \
                    AF[ks_][mm_], BF[ks_][nn_], acc[(MI0) + mm_][(NJ0) + nn_], 0, 0, 0); \
    __builtin_amdgcn_s_setprio(0); }

// One K-tile: lag-1 full-dbuf staging, ONE vmcnt + ONE barrier.
#define KTILE(PBUF, KT, S, SR, VMOP) { \
    const int t1off_ = k_off((KT) + 1); \
    unsigned short* aC_ = smem + (PBUF) * 16384 + wmIdx * 8192; \
    unsigned short* bC_ = smem + 32768 + (PBUF) * 16384 + bHalfSel * 8192; \
    unsigned short* aN_ = smem + ((PBUF) ^ 1) * 16384 + wmIdx * 8192; \
    unsigned short* bN_ = smem + 32768 + ((PBUF) ^ 1) * 16384 + bHalfSel * 8192; \
    /* region 1 */ \
    READ_A(aHi, aC_, 4) \
    if (S) { STAGE_A(t1off_, 0, (PBUF) ^ 1) STAGE_A(t1off_, 1, (PBUF) ^ 1) \
             STAGE_B(t1off_, 0, (PBUF) ^ 1) STAGE_B(t1off_, 1, (PBUF) ^ 1) } \
    QUAD(aLo, bLo, 0, 0) \
    READ_B(bHi, bC_, 2) \
    QUAD(aHi, bLo, 4, 0) \
    QUAD(aLo, bHi, 0, 2) \
    VMOP; \
    BAR \
    __builtin_amdgcn_sched_barrier(0); \
    /* region 2 */ \
    if (SR) { READ_A(aLo, aN_, 0) READ_B(bLo, bN_, 0) } \
    QUAD(aHi, bHi, 4, 2) \
}

__global__ __launch_bounds__(512, 2) void gemm_bf16_8ph(
    const unsigned short* __restrict__ A,  // [R, M, K_LOCAL] bf16
    const unsigned short* __restrict__ B,  // [R, N, K_LOCAL] bf16
    float* __restrict__ C) {               // [M, N] fp32
    extern __shared__ unsigned short smem[];  // 131072 B

    const int tid = threadIdx.x;
    const int lane = tid & 63;
    const int wave = tid >> 6;        // 0..7
    const int wmIdx = wave >> 2;      // 0..1  (128-row M half)
    const int wn = wave & 3;          // 0..3  (64-col N slice)
    const int l15 = lane & 15;
    const int l4 = lane >> 4;
    const int bHalfSel = wn >> 1;
    const int bRowBase = (wn & 1) * 64;

    // XCD-aware mapping: 16x16 tile grid; XCD x owns an 8x4 region.
    const int bid = blockIdx.x;       // 0..255
    const int xcd = bid & 7;
    const int idx = bid >> 3;         // 0..31
    const int tm = (xcd >> 2) * 8 + (idx >> 2);
    const int tn = (xcd & 3) * 4 + (idx & 3);
    const int bm0 = tm * 256;
    const int bn0 = tn * 256;

    // Staging offsets: half-tile = 128 rows x 64 cols; chunk cc = j*512 + tid
    // -> (row = cc>>3, pos = cc&7), XOR swizzle applied on the global source.
    int thrA[2], thrB[2], ldsOff[2];
#pragma unroll
    for (int j = 0; j < 2; ++j) {
        int cc = j * 512 + tid;
        int row = cc >> 3;
        int col = ((cc & 7) ^ (row & 7)) * 8;
        thrA[j] = (bm0 + row) * K_LOCAL + col;
        thrB[j] = (bn0 + row) * K_LOCAL + col;
        ldsOff[j] = cc * 8;
    }

    const int swz0 = ((0 + l4) ^ (l15 & 7)) * 8;  // ks = 0
    const int swz1 = ((4 + l4) ^ (l15 & 7)) * 8;  // ks = 1

    bf16x8 aLo[2][4], aHi[2][4], bLo[2][2], bHi[2][2];
    f32x4 acc[8][4] = {};

    // Prologue: stage tile0 into buf0 (8 loads); drain; preload aLo/bLo(0).
    STAGE_A(0, 0, 0)
    STAGE_A(0, 1, 0)
    STAGE_B(0, 0, 0)
    STAGE_B(0, 1, 0)
    VM0;
    BAR
    READ_A(aLo, smem + wmIdx * 8192, 0)
    READ_B(bLo, smem + 32768 + bHalfSel * 8192, 0)

#pragma unroll 1
    for (int kt = 0; kt < 126; kt += 2) {
        KTILE(0, kt, 1, 1, VM0)
        KTILE(1, kt + 1, 1, 1, VM0)
    }
    KTILE(0, 126, 1, 1, VM0)        // stages tile 127 -> buf1; reads its lo frags
    KTILE(1, 127, 0, 0, VMNONE)     // pure compute (extra barrier harmless)

    // epilogue: C/D layout col = lane&15, row = (lane>>4)*4 + reg
#pragma unroll
    for (int mi = 0; mi < 8; ++mi) {
        int row0 = bm0 + wmIdx * 128 + mi * 16 + l4 * 4;
#pragma unroll
        for (int nj = 0; nj < 4; ++nj) {
            int col = bn0 + wn * 64 + nj * 16 + l15;
#pragma unroll
            for (int r = 0; r < 4; ++r)
                C[(size_t)(row0 + r) * N_DIM + col] = acc[mi][nj][r];
        }
    }
}

// ---------- Fallback A: 128x128 m97-structure kernel ----------
__global__ __launch_bounds__(256) void gemm_bf16_128(
    const unsigned short* __restrict__ A,
    const unsigned short* __restrict__ B,
    float* __restrict__ C) {
    __shared__ __align__(16) unsigned short As[128 * 64];
    __shared__ __align__(16) unsigned short Bs[128 * 64];

    const int tid = threadIdx.x;
    const int lane = tid & 63;
    const int wave = tid >> 6;
    const int wm = (wave >> 1) * 64;
    const int wnn = (wave & 1) * 64;
    const int l15 = lane & 15;
    const int l4 = lane >> 4;

    const int bid = blockIdx.x;
    const int xcd = bid & 7;
    const int q = bid >> 3;
    const int st = (q >> 2) * 8 + xcd;
    const int pos = q & 3;
    const int bm0 = ((st >> 4) * 2 + (pos >> 1)) * 128;
    const int bn0 = ((st & 15) * 2 + (pos & 1)) * 128;

    const unsigned short* ga[4];
    const unsigned short* gb[4];
    int lo[4];
#pragma unroll
    for (int p = 0; p < 4; ++p) {
        int cc = p * 256 + tid;
        int row = cc >> 3;
        int cpos = cc & 7;
        int col = (cpos ^ (row & 7)) * 8;
        ga[p] = A + (size_t)(bm0 + row) * K_LOCAL + col;
        gb[p] = B + (size_t)(bn0 + row) * K_LOCAL + col;
        lo[p] = cc * 8;
    }

    const int swz0 = ((l4 + 0) ^ (l15 & 7)) * 8;
    const int swz1 = ((l4 + 4) ^ (l15 & 7)) * 8;
    const int a_row = (wm + l15) * 64;
    const int b_row = (wnn + l15) * 64;

    f32x4 acc[4][4] = {};

    for (int r = 0; r < RANKS; ++r) {
        const size_t roff = (size_t)r * (M_DIM * (size_t)K_LOCAL);
        for (int kl = 0; kl < K_LOCAL; kl += 64) {
#pragma unroll
            for (int p = 0; p < 4; ++p) {
                gll16(ga[p] + roff + kl, &As[lo[p]]);
                gll16(gb[p] + roff + kl, &Bs[lo[p]]);
            }
            __syncthreads();
#pragma unroll
            for (int ks = 0; ks < 2; ++ks) {
                const int swz = ks ? swz1 : swz0;
                bf16x8 af[4], bfr[4];
#pragma unroll
                for (int i = 0; i < 4; ++i)
                    af[i] = *(const bf16x8*)&As[a_row + i * 16 * 64 + swz];
#pragma unroll
                for (int j = 0; j < 4; ++j)
                    bfr[j] = *(const bf16x8*)&Bs[b_row + j * 16 * 64 + swz];
#pragma unroll
                for (int i = 0; i < 4; ++i)
#pragma unroll
                    for (int j = 0; j < 4; ++j)
                        acc[i][j] = __builtin_amdgcn_mfma_f32_16x16x32_bf16(
                            af[i], bfr[j], acc[i][j], 0, 0, 0);
            }
            __syncthreads();
        }
    }

#pragma unroll
    for (int i = 0; i < 4; ++i) {
        int row0 = bm0 + wm + i * 16 + l4 * 4;
#pragma unroll
        for (int j = 0; j < 4; ++j) {
            int col = bn0 + wnn + j * 16 + l15;
#pragma unroll
            for (int r = 0; r < 4; ++r)
                C[(size_t)(row0 + r) * N_DIM + col] = acc[i][j][r];
        }
    }
}

// ---------- Fallback B (ws too small): naive fp32 tiled GEMM ----------
__global__ void gemm_naive(const float* __restrict__ A, const float* __restrict__ B,
                           float* __restrict__ C) {
    __shared__ float As[16][17];
    __shared__ float Bs[16][17];
    int tx = threadIdx.x, ty = threadIdx.y;
    int m = blockIdx.y * 16 + ty;
    int n0 = blockIdx.x * 16;
    float accv = 0.f;
    for (int kt = 0; kt < K_DIM; kt += 16) {
        int r = kt >> 10;
        int k = (kt & 1023) + tx;
        As[ty][tx] = A[((size_t)r * M_DIM + m) * K_LOCAL + k];
        Bs[ty][tx] = B[((size_t)r * N_DIM + (n0 + ty)) * K_LOCAL + k];
        __syncthreads();
#pragma unroll
        for (int kk = 0; kk < 16; ++kk) accv += As[ty][kk] * Bs[tx][kk];
        __syncthreads();
    }
    C[(size_t)m * N_DIM + n0 + tx] = accv;
}

extern "C" void kernel_launch(void* const* d_in, const int* in_sizes, int n_in,
                              void* d_out, int out_size, void* d_ws, size_t ws_size,
                              hipStream_t stream) {
    const float* inp = (const float*)d_in[0];
    const float* wgt = (const float*)d_in[1];
    float* out = (float*)d_out;

    const size_t elems = (size_t)M_DIM * K_DIM;              // 33,554,432 per tensor
    const size_t need = 2 * elems * sizeof(unsigned short);  // 128 MiB

    if (ws_size >= need) {
        unsigned short* Abf = (unsigned short*)d_ws;
        unsigned short* Bbf = Abf + elems;
        const int bpt = (int)(elems / 4096);  // 8192 blocks per tensor
        convert_cast<<<bpt * 2, 256, 0, stream>>>(inp, Abf, wgt, Bbf, bpt);

        static int dynOK = -1;
        if (dynOK < 0) {
            dynOK = (hipFuncSetAttribute((const void*)gemm_bf16_8ph,
                                         hipFuncAttributeMaxDynamicSharedMemorySize,
                                         131072) == hipSuccess)
                        ? 1
                        : 0;
        }
        if (dynOK) {
            gemm_bf16_8ph<<<256, 512, 131072, stream>>>(Abf, Bbf, out);
        } else {
            gemm_bf16_128<<<1024, 256, 0, stream>>>(Abf, Bbf, out);
        }
    } else {
        dim3 grid(N_DIM / 16, M_DIM / 16);
        dim3 block(16, 16);
        gemm_naive<<<grid, block, 0, stream>>>(inp, wgt, out);
    }
}